// Round 4
// baseline (139.793 us; speedup 1.0000x reference)
//
#include <hip/hip_runtime.h>
#include <math.h>

#define KW 5
#define BETA 15.0f
#define MSHIFT 3.0f
#define CIN 8
#define COUT 8
#define HH 256
#define WW 256
#define TW 32      // tile width  (2 groups of 16 px)
#define THT 16     // tile height
#define CWp 36     // TW + 4 halo
#define CHp 20     // THT + 4 halo

typedef float f32x4 __attribute__((ext_vector_type(4)));
typedef short s16x8 __attribute__((ext_vector_type(8)));

static __device__ __forceinline__ unsigned f2bf(float f) {
    unsigned u = __float_as_uint(f);
    return (u + 0x7FFFu + ((u >> 16) & 1u)) >> 16;  // RNE
}

// Exp-space 5x5 conv as implicit GEMM on matrix cores (same math as R3):
// out = M + log(sum_{c,tap} exp(beta(x-M)) * exp(beta w)) / beta.
// k = tap*8 + c (25 taps padded to 28 = 7 K32 steps, pad rows of A = 0).
// A (M=16 = o, 8 used): exp(beta*w) VGPR-resident. B (N=16 = px) from LDS,
// channel-fastest bf16 so one k-quad slice is a single ds_read_b128.
// D: col=lane&15=px, row=quad*4+reg=o.
// Tile 32x16, LDS 11.5 KB -> 8 blocks/CU = 32 waves/CU (max occupancy).
__global__ __launch_bounds__(256, 8) void morph_mfma(
    const float* __restrict__ x, const float* __restrict__ wgt,
    float* __restrict__ out)
{
    __shared__ int4 exs[CHp * CWp];  // 720 * 16 B = 11520 B

    const int tid  = threadIdx.x;
    const int lane = tid & 63;
    const int wv   = tid >> 6;     // wave -> output rows wv*4 .. wv*4+3
    const int px   = lane & 15;
    const int quad = lane >> 4;

    // XCD-contiguous swizzle: 2048 blocks = 8 XCD * 256; XCD k gets 2 batches.
    const int lid = blockIdx.x;
    const int sw  = (lid & 7) * 256 + (lid >> 3);
    const int b   = sw >> 7;
    const int t   = sw & 127;                 // 16 h-tiles * 8 w-tiles
    const int h0  = (t >> 3) * THT;
    const int w0  = (t & 7) * TW;

    // ---- A fragments (weights) + per-lane tap offsets ----
    s16x8 afrag[7];
    int   toff[7];
    #pragma unroll
    for (int g = 0; g < 7; ++g) {
        int tap = g * 4 + quad;
        int tc  = tap < 25 ? tap : 24;        // clamp addr; A=0 kills pad taps
        toff[g] = (tc / KW) * CWp + (tc % KW);
        s16x8 af;
        #pragma unroll
        for (int j = 0; j < 8; ++j) {         // j = c
            float v = 0.0f;
            if (tap < 25 && px < COUT)
                v = __expf(BETA * wgt[(px * CIN + j) * (KW * KW) + tap]);
            af[j] = (short)f2bf(v);
        }
        afrag[g] = af;
    }

    // ---- stage exp(beta*(x-M)), bf16 channel-fastest; float4 along w ----
    // One work item = 4 consecutive cols x all 8 channels. 20 rows * 9 quads.
    for (int s = tid; s < CHp * (CWp / 4); s += 256) {
        int r  = s / (CWp / 4);
        int q  = s - r * (CWp / 4);
        int gh = h0 + r - 2;
        int gw0 = w0 + 4 * q - 2;
        bool rowok = (unsigned)gh < (unsigned)HH;
        bool fast  = rowok & (gw0 >= 0) & (gw0 + 3 < WW);
        unsigned pk[4][4];   // [col][c-pair]
        #pragma unroll
        for (int c = 0; c < CIN; ++c) {
            float v[4];
            if (fast) {
                const float4 f = *(const float4*)&x[((b * CIN + c) * HH + gh) * WW + gw0];
                v[0] = f.x; v[1] = f.y; v[2] = f.z; v[3] = f.w;
            } else {
                #pragma unroll
                for (int e = 0; e < 4; ++e) {
                    int gw = gw0 + e;
                    v[e] = (rowok && (unsigned)gw < (unsigned)WW)
                         ? x[((b * CIN + c) * HH + gh) * WW + gw] : 0.0f;
                }
            }
            #pragma unroll
            for (int e = 0; e < 4; ++e) {
                unsigned bfv = f2bf(__expf(BETA * (v[e] - MSHIFT)));
                if (c & 1) pk[e][c >> 1] |= bfv << 16;
                else       pk[e][c >> 1]  = bfv;
            }
        }
        #pragma unroll
        for (int e = 0; e < 4; ++e) {
            int4 p; p.x = pk[e][0]; p.y = pk[e][1]; p.z = pk[e][2]; p.w = pk[e][3];
            exs[r * CWp + 4 * q + e] = p;
        }
    }
    __syncthreads();

    // ---- main: 8 px-groups/wave, 7 MFMA each; split acc chain 4+3 ----
    const float inv_beta = 1.0f / BETA;
    #pragma unroll
    for (int wb = 0; wb < 2; ++wb) {
        #pragma unroll
        for (int hl = 0; hl < 4; ++hl) {
            const int hh   = wv * 4 + hl;
            const int base = hh * CWp + wb * 16 + px;
            f32x4 acc0 = {0.0f, 0.0f, 0.0f, 0.0f};
            f32x4 acc1 = {0.0f, 0.0f, 0.0f, 0.0f};
            #pragma unroll
            for (int g = 0; g < 7; ++g) {
                s16x8 bfr = *(const s16x8*)&exs[base + toff[g]];
                if (g & 1)
                    acc1 = __builtin_amdgcn_mfma_f32_16x16x32_bf16(
                               afrag[g], bfr, acc1, 0, 0, 0);
                else
                    acc0 = __builtin_amdgcn_mfma_f32_16x16x32_bf16(
                               afrag[g], bfr, acc0, 0, 0, 0);
            }
            if (quad < 2) {
                #pragma unroll
                for (int r = 0; r < 4; ++r) {
                    int o = quad * 4 + r;
                    out[((b * COUT + o) * HH + h0 + hh) * WW + w0 + wb * 16 + px]
                        = MSHIFT + __logf(acc0[r] + acc1[r]) * inv_beta;
                }
            }
        }
    }
}

extern "C" void kernel_launch(void* const* d_in, const int* in_sizes, int n_in,
                              void* d_out, int out_size, void* d_ws, size_t ws_size,
                              hipStream_t stream) {
    const float* x   = (const float*)d_in[0];
    const float* wgt = (const float*)d_in[1];
    float* out = (float*)d_out;

    const int B = in_sizes[0] / (CIN * HH * WW);          // 16
    const int nblk = B * (HH / THT) * (WW / TW);          // 2048
    morph_mfma<<<nblk, 256, 0, stream>>>(x, wgt, out);
}

// Round 5
// 129.239 us; speedup vs baseline: 1.0817x; 1.0817x over previous
//
#include <hip/hip_runtime.h>
#include <math.h>

#define KW 5
#define BETA 15.0f
#define MSHIFT 3.0f
#define CIN 8
#define COUT 8
#define HH 256
#define WW 256
#define TW 64      // tile width  (4 groups of 16 px; 256-B rows -> clean sectors)
#define THT 16     // tile height
#define CWp 68     // TW + 4 halo
#define CHp 20     // THT + 4 halo

typedef float f32x4 __attribute__((ext_vector_type(4)));
typedef short s16x8 __attribute__((ext_vector_type(8)));

static __device__ __forceinline__ unsigned f2bf(float f) {
    unsigned u = __float_as_uint(f);
    return (u + 0x7FFFu + ((u >> 16) & 1u)) >> 16;  // RNE
}

// Exp-space 5x5 conv as implicit GEMM on matrix cores:
// out = M + log(sum_{c,tap} exp(beta(x-M)) * exp(beta w)) / beta.
// k = tap*8 + c (25 taps padded to 28 = 7 K32 steps; pad rows of A = 0).
// A (M=16 = o, 8 used): exp(beta*w), VGPR-resident. B (N=16 = px) from LDS,
// channel-fastest bf16 so one k-quad slice is a single ds_read_b128.
// D: col=lane&15=px, row=quad*4+reg=o.
// R5: R3's 64x16 tile (measured-clean HBM: WRITE 32.9 MB) with 512-thread
// blocks -> 4 blk/CU x 8 waves = 32 waves/CU (max occupancy, was R3's stall).
__global__ __launch_bounds__(512, 8) void morph_mfma(
    const float* __restrict__ x, const float* __restrict__ wgt,
    float* __restrict__ out)
{
    __shared__ int4 exs[CHp * CWp];  // 1360 * 16 B = 21760 B; 4 blk/CU = 87 KB

    const int tid  = threadIdx.x;
    const int lane = tid & 63;
    const int wv   = tid >> 6;     // wave 0..7 -> output rows 2*wv, 2*wv+1
    const int px   = lane & 15;
    const int quad = lane >> 4;

    // XCD-contiguous swizzle: 1024 blocks = 8 XCD * 128; XCD k gets 2 batches.
    const int lid = blockIdx.x;
    const int sw  = (lid & 7) * 128 + (lid >> 3);
    const int b   = sw >> 6;
    const int t   = sw & 63;                  // 16 h-tiles * 4 w-tiles
    const int h0  = (t >> 2) * THT;
    const int w0  = (t & 3) * TW;

    // ---- A fragments (weights) + per-lane tap offsets ----
    s16x8 afrag[7];
    int   toff[7];
    #pragma unroll
    for (int g = 0; g < 7; ++g) {
        int tap = g * 4 + quad;
        int tc  = tap < 25 ? tap : 24;        // clamp addr; A=0 kills pad taps
        toff[g] = (tc / KW) * CWp + (tc % KW);
        s16x8 af;
        #pragma unroll
        for (int j = 0; j < 8; ++j) {         // j = c
            float v = 0.0f;
            if (tap < 25 && px < COUT)
                v = __expf(BETA * wgt[(px * CIN + j) * (KW * KW) + tap]);
            af[j] = (short)f2bf(v);
        }
        afrag[g] = af;
    }

    // ---- stage exp(beta*(x-M)) halo tile, bf16 channel-fastest ----
    // One slot per thread (R3 pattern: contiguous lanes -> conflict-free
    // ds_write_b128; 8 independent strided loads hide under 32 waves/CU).
    for (int s = tid; s < CHp * CWp; s += 512) {
        int r = s / CWp, col = s - r * CWp;
        int gh = h0 + r - 2, gw = w0 + col - 2;
        bool ok = ((unsigned)gh < (unsigned)HH) & ((unsigned)gw < (unsigned)WW);
        unsigned pk[4];
        #pragma unroll
        for (int c2 = 0; c2 < 4; ++c2) {
            float v0 = 0.0f, v1 = 0.0f;
            if (ok) {
                v0 = x[((b * CIN + 2 * c2) * HH + gh) * WW + gw];
                v1 = x[((b * CIN + 2 * c2 + 1) * HH + gh) * WW + gw];
            }
            unsigned lo = f2bf(__expf(BETA * (v0 - MSHIFT)));
            unsigned hi = f2bf(__expf(BETA * (v1 - MSHIFT)));
            pk[c2] = lo | (hi << 16);
        }
        int4 p; p.x = pk[0]; p.y = pk[1]; p.z = pk[2]; p.w = pk[3];
        exs[s] = p;
    }
    __syncthreads();

    // ---- main: 2 rows/wave, 4 wb-groups/row, 7 MFMA each (K=224) ----
    // wb inner + store-per-group: the 4 chunks of each 256-B out sector are
    // issued within ~30 instructions of each other.
    const float inv_beta = 1.0f / BETA;
    #pragma unroll
    for (int hl = 0; hl < 2; ++hl) {
        const int hh = wv * 2 + hl;
        #pragma unroll
        for (int wb = 0; wb < 4; ++wb) {
            const int base = hh * CWp + wb * 16 + px;
            f32x4 acc0 = {0.0f, 0.0f, 0.0f, 0.0f};
            f32x4 acc1 = {0.0f, 0.0f, 0.0f, 0.0f};
            #pragma unroll
            for (int g = 0; g < 7; ++g) {
                s16x8 bfr = *(const s16x8*)&exs[base + toff[g]];
                if (g & 1)
                    acc1 = __builtin_amdgcn_mfma_f32_16x16x32_bf16(
                               afrag[g], bfr, acc1, 0, 0, 0);
                else
                    acc0 = __builtin_amdgcn_mfma_f32_16x16x32_bf16(
                               afrag[g], bfr, acc0, 0, 0, 0);
            }
            if (quad < 2) {
                #pragma unroll
                for (int r = 0; r < 4; ++r) {
                    int o = quad * 4 + r;
                    out[((b * COUT + o) * HH + h0 + hh) * WW + w0 + wb * 16 + px]
                        = MSHIFT + __logf(acc0[r] + acc1[r]) * inv_beta;
                }
            }
        }
    }
}

extern "C" void kernel_launch(void* const* d_in, const int* in_sizes, int n_in,
                              void* d_out, int out_size, void* d_ws, size_t ws_size,
                              hipStream_t stream) {
    const float* x   = (const float*)d_in[0];
    const float* wgt = (const float*)d_in[1];
    float* out = (float*)d_out;

    const int B = in_sizes[0] / (CIN * HH * WW);          // 16
    const int nblk = B * (HH / THT) * (WW / TW);          // 1024
    morph_mfma<<<nblk, 512, 0, stream>>>(x, wgt, out);
}

// Round 6
// 118.637 us; speedup vs baseline: 1.1783x; 1.0894x over previous
//
#include <hip/hip_runtime.h>
#include <math.h>

#define KW 5
#define BETA 15.0f
#define MSHIFT 3.0f
#define CIN 8
#define COUT 8
#define HH 256
#define WW 256
#define TW 64      // tile width  (4 groups of 16 px; 256-B rows -> clean sectors)
#define THT 16     // tile height
#define CWp 68     // TW + 4 halo
#define CHp 20     // THT + 4 halo

typedef float f32x4 __attribute__((ext_vector_type(4)));
typedef short s16x8 __attribute__((ext_vector_type(8)));

static __device__ __forceinline__ unsigned f2bf(float f) {
    unsigned u = __float_as_uint(f);
    return (u + 0x7FFFu + ((u >> 16) & 1u)) >> 16;  // RNE
}

// Exp-space 5x5 conv as implicit GEMM on matrix cores:
// out = M + log(sum_{c,tap} exp(beta(x-M)) * exp(beta w)) / beta.
// k = tap*8 + c (25 taps padded to 28 = 7 K32 steps; pad rows of A = 0).
// A (M=16 = o, 8 used): exp(beta*w), VGPR-resident. B (N=16 = px) from LDS,
// channel-fastest bf16 so one k-quad slice is a single ds_read_b128.
// D: col=lane&15=px, row=quad*4+reg=o.
//
// R6: launch_bounds min-waves MUST stay 4. R4/R5 used 8 -> 64-VGPR cap ->
// afrag (28 VGPRs) spilled to scratch (VGPR_Count dropped to 32, hbm_bytes
// 2-4x ideal, inner loop reloading A from scratch). At budget 128 the same
// code compiled to 52 VGPRs (R3) -> 8 waves/EU still reachable, no spills.
__global__ __launch_bounds__(512, 4) void morph_mfma(
    const float* __restrict__ x, const float* __restrict__ wgt,
    float* __restrict__ out)
{
    __shared__ int4 exs[CHp * CWp];  // 1360 * 16 B = 21760 B

    const int tid  = threadIdx.x;
    const int lane = tid & 63;
    const int wv   = tid >> 6;     // wave 0..7 -> output rows 2*wv, 2*wv+1
    const int px   = lane & 15;
    const int quad = lane >> 4;

    // XCD-contiguous swizzle: 1024 blocks = 8 XCD * 128; XCD k gets 2 batches.
    const int lid = blockIdx.x;
    const int sw  = (lid & 7) * 128 + (lid >> 3);
    const int b   = sw >> 6;
    const int t   = sw & 63;                  // 16 h-tiles * 4 w-tiles
    const int h0  = (t >> 2) * THT;
    const int w0  = (t & 3) * TW;

    // ---- stage exp(beta*(x-M)) halo tile, bf16 channel-fastest ----
    // Issued FIRST so afrag setup below overlaps the staging load latency.
    for (int s = tid; s < CHp * CWp; s += 512) {
        int r = s / CWp, col = s - r * CWp;
        int gh = h0 + r - 2, gw = w0 + col - 2;
        bool ok = ((unsigned)gh < (unsigned)HH) & ((unsigned)gw < (unsigned)WW);
        unsigned pk[4];
        #pragma unroll
        for (int c2 = 0; c2 < 4; ++c2) {
            float v0 = 0.0f, v1 = 0.0f;
            if (ok) {
                v0 = x[((b * CIN + 2 * c2) * HH + gh) * WW + gw];
                v1 = x[((b * CIN + 2 * c2 + 1) * HH + gh) * WW + gw];
            }
            unsigned lo = f2bf(__expf(BETA * (v0 - MSHIFT)));
            unsigned hi = f2bf(__expf(BETA * (v1 - MSHIFT)));
            pk[c2] = lo | (hi << 16);
        }
        int4 p; p.x = pk[0]; p.y = pk[1]; p.z = pk[2]; p.w = pk[3];
        exs[s] = p;  // contiguous lanes -> conflict-free ds_write_b128
    }

    // ---- A fragments (weights) + per-lane tap offsets ----
    s16x8 afrag[7];
    int   toff[7];
    #pragma unroll
    for (int g = 0; g < 7; ++g) {
        int tap = g * 4 + quad;
        int tc  = tap < 25 ? tap : 24;        // clamp addr; A=0 kills pad taps
        toff[g] = (tc / KW) * CWp + (tc % KW);
        s16x8 af;
        #pragma unroll
        for (int j = 0; j < 8; ++j) {         // j = c
            float v = 0.0f;
            if (tap < 25 && px < COUT)
                v = __expf(BETA * wgt[(px * CIN + j) * (KW * KW) + tap]);
            af[j] = (short)f2bf(v);
        }
        afrag[g] = af;
    }
    __syncthreads();

    // ---- main: 2 rows/wave, 4 wb-groups/row, 7 MFMA each (K=224) ----
    const float inv_beta = 1.0f / BETA;
    #pragma unroll
    for (int hl = 0; hl < 2; ++hl) {
        const int hh = wv * 2 + hl;
        #pragma unroll
        for (int wb = 0; wb < 4; ++wb) {
            const int base = hh * CWp + wb * 16 + px;
            f32x4 acc0 = {0.0f, 0.0f, 0.0f, 0.0f};
            f32x4 acc1 = {0.0f, 0.0f, 0.0f, 0.0f};
            #pragma unroll
            for (int g = 0; g < 7; ++g) {
                s16x8 bfr = *(const s16x8*)&exs[base + toff[g]];
                if (g & 1)
                    acc1 = __builtin_amdgcn_mfma_f32_16x16x32_bf16(
                               afrag[g], bfr, acc1, 0, 0, 0);
                else
                    acc0 = __builtin_amdgcn_mfma_f32_16x16x32_bf16(
                               afrag[g], bfr, acc0, 0, 0, 0);
            }
            if (quad < 2) {
                #pragma unroll
                for (int r = 0; r < 4; ++r) {
                    int o = quad * 4 + r;
                    out[((b * COUT + o) * HH + h0 + hh) * WW + w0 + wb * 16 + px]
                        = MSHIFT + __logf(acc0[r] + acc1[r]) * inv_beta;
                }
            }
        }
    }
}

extern "C" void kernel_launch(void* const* d_in, const int* in_sizes, int n_in,
                              void* d_out, int out_size, void* d_ws, size_t ws_size,
                              hipStream_t stream) {
    const float* x   = (const float*)d_in[0];
    const float* wgt = (const float*)d_in[1];
    float* out = (float*)d_out;

    const int B = in_sizes[0] / (CIN * HH * WW);          // 16
    const int nblk = B * (HH / THT) * (WW / TW);          // 1024
    morph_mfma<<<nblk, 512, 0, stream>>>(x, wgt, out);
}

// Round 7
// 99.421 us; speedup vs baseline: 1.4061x; 1.1933x over previous
//
#include <hip/hip_runtime.h>
#include <hip/hip_bf16.h>
#include <math.h>

#define KW 5
#define BETA 15.0f
#define MSHIFT 3.0f
#define CIN 8
#define COUT 8
#define HH 256
#define WW 256
#define TW 64      // tile width (4 groups of 16 px; 256-B rows -> clean sectors)
#define THT 8      // tile height (grid 2048 -> 8 blocks/CU, desynced phases)
#define CWp 68     // TW + 4 halo
#define CHp 12     // THT + 4 halo

typedef float f32x4 __attribute__((ext_vector_type(4)));
typedef short s16x8 __attribute__((ext_vector_type(8)));

static __device__ __forceinline__ unsigned f2bf(float f) {
    unsigned u = __float_as_uint(f);
    return (u + 0x7FFFu + ((u >> 16) & 1u)) >> 16;  // RNE
}

// Pre-kernel: build A-fragment table in exact MFMA A-operand layout.
// table[g*64 + lane] = 8 bf16 = exp(beta*w[row=lane&15][c=j][tap=g*4+quad]),
// zero for pad taps (>=25) and unused rows (>=8). 448 entries, 7168 B.
__global__ void build_afrag(const float* __restrict__ wgt,
                            s16x8* __restrict__ table) {
    int i = blockIdx.x * 64 + threadIdx.x;       // 0..447
    if (i >= 7 * 64) return;
    int g = i >> 6, lane = i & 63;
    int quad = lane >> 4, row = lane & 15;
    int tap = g * 4 + quad;
    s16x8 af;
    #pragma unroll
    for (int j = 0; j < CIN; ++j) {
        float v = 0.0f;
        if (tap < 25 && row < COUT)
            v = __expf(BETA * wgt[(row * CIN + j) * (KW * KW) + tap]);
        af[j] = (short)f2bf(v);
    }
    table[i] = af;
}

// Exp-space 5x5 conv as implicit GEMM on matrix cores:
// out = M + log(sum_{c,tap} exp(beta(x-M)) * exp(beta w)) / beta.
// k = tap*8 + c (25 taps padded to 28 = 7 K32 steps; pad rows of A = 0).
// A from precomputed table (7 coalesced dwordx4, L2-hot). B (N=16 px) from
// LDS, channel-fastest bf16 -> one k-quad slice = one ds_read_b128.
// D: col=lane&15=px, row=quad*4+reg=o.
// launch_bounds min-waves: 4/R6 ok, 8 spilled afrag (R4/R5: VGPR_Count 32,
// 2-4x hbm traffic). 6 -> 80-VGPR cap, need ~60: safe.
__global__ __launch_bounds__(256, 6) void morph_mfma(
    const float* __restrict__ x, const s16x8* __restrict__ table,
    float* __restrict__ out)
{
    __shared__ int4 exs[CHp * CWp];  // 816 * 16 B = 13056 B -> 8+ blocks/CU

    const int tid  = threadIdx.x;
    const int lane = tid & 63;
    const int wv   = tid >> 6;     // wave 0..3 -> output rows 2*wv, 2*wv+1
    const int px   = lane & 15;
    const int quad = lane >> 4;

    // XCD-contiguous swizzle: 2048 blocks = 8 XCD * 256; XCD k gets 2 batches.
    const int lid = blockIdx.x;
    const int sw  = (lid & 7) * 256 + (lid >> 3);
    const int b   = sw >> 7;
    const int t   = sw & 127;                 // 32 h-tiles * 4 w-tiles
    const int h0  = (t >> 2) * THT;
    const int w0  = (t & 3) * TW;

    // ---- A fragments: 7 coalesced 16-B loads (issued first, used after
    // the barrier -> latency fully hidden under staging) ----
    s16x8 afrag[7];
    int   toff[7];
    #pragma unroll
    for (int g = 0; g < 7; ++g) {
        afrag[g] = table[g * 64 + lane];
        int tap = g * 4 + quad;
        int tc  = tap < 25 ? tap : 24;        // clamp addr; A=0 kills pad taps
        toff[g] = (tc / KW) * CWp + (tc % KW);
    }

    // ---- stage exp(beta*(x-M)) halo tile, bf16 channel-fastest ----
    for (int s = tid; s < CHp * CWp; s += 256) {
        int r = s / CWp, col = s - r * CWp;
        int gh = h0 + r - 2, gw = w0 + col - 2;
        bool ok = ((unsigned)gh < (unsigned)HH) & ((unsigned)gw < (unsigned)WW);
        unsigned pk[4];
        #pragma unroll
        for (int c2 = 0; c2 < 4; ++c2) {
            float v0 = 0.0f, v1 = 0.0f;
            if (ok) {
                v0 = x[((b * CIN + 2 * c2) * HH + gh) * WW + gw];
                v1 = x[((b * CIN + 2 * c2 + 1) * HH + gh) * WW + gw];
            }
            float2 e = make_float2(__expf(BETA * (v0 - MSHIFT)),
                                   __expf(BETA * (v1 - MSHIFT)));
            __hip_bfloat162 h2 = __float22bfloat162_rn(e);  // v_cvt_pk_bf16_f32
            pk[c2] = *reinterpret_cast<unsigned*>(&h2);
        }
        int4 p; p.x = pk[0]; p.y = pk[1]; p.z = pk[2]; p.w = pk[3];
        exs[s] = p;  // contiguous lanes -> conflict-free ds_write_b128
    }
    __syncthreads();

    // ---- main: 2 rows/wave, 4 wb-groups/row, 7 MFMA each (K=224) ----
    const float inv_beta = 1.0f / BETA;
    #pragma unroll
    for (int hl = 0; hl < 2; ++hl) {
        const int hh = wv * 2 + hl;
        #pragma unroll
        for (int wb = 0; wb < 4; ++wb) {
            const int base = hh * CWp + wb * 16 + px;
            f32x4 acc0 = {0.0f, 0.0f, 0.0f, 0.0f};
            f32x4 acc1 = {0.0f, 0.0f, 0.0f, 0.0f};
            #pragma unroll
            for (int g = 0; g < 7; ++g) {
                s16x8 bfr = *(const s16x8*)&exs[base + toff[g]];
                if (g & 1)
                    acc1 = __builtin_amdgcn_mfma_f32_16x16x32_bf16(
                               afrag[g], bfr, acc1, 0, 0, 0);
                else
                    acc0 = __builtin_amdgcn_mfma_f32_16x16x32_bf16(
                               afrag[g], bfr, acc0, 0, 0, 0);
            }
            if (quad < 2) {
                #pragma unroll
                for (int r = 0; r < 4; ++r) {
                    int o = quad * 4 + r;
                    out[((b * COUT + o) * HH + h0 + hh) * WW + w0 + wb * 16 + px]
                        = MSHIFT + __logf(acc0[r] + acc1[r]) * inv_beta;
                }
            }
        }
    }
}

extern "C" void kernel_launch(void* const* d_in, const int* in_sizes, int n_in,
                              void* d_out, int out_size, void* d_ws, size_t ws_size,
                              hipStream_t stream) {
    const float* x   = (const float*)d_in[0];
    const float* wgt = (const float*)d_in[1];
    float* out  = (float*)d_out;
    s16x8* tab  = (s16x8*)d_ws;   // 7168 B, ws is far larger

    const int B = in_sizes[0] / (CIN * HH * WW);          // 16
    const int nblk = B * (HH / THT) * (WW / TW);          // 2048

    build_afrag<<<7, 64, 0, stream>>>(wgt, tab);
    morph_mfma<<<nblk, 256, 0, stream>>>(x, tab, out);
}

// Round 8
// 98.615 us; speedup vs baseline: 1.4176x; 1.0082x over previous
//
#include <hip/hip_runtime.h>
#include <hip/hip_bf16.h>
#include <math.h>

#define KW 5
#define BETA 15.0f
#define MSHIFT 3.0f
#define CIN 8
#define COUT 8
#define HH 256
#define WW 256
#define TWW 16     // wave tile width  (one 16-px MFMA N-group)
#define TWH 8      // wave tile height
#define WCW 20     // TWW + 4 halo
#define WCH 12     // TWH + 4 halo
#define WSLOTS (WCW * WCH)   // 240 slots/wave

typedef float f32x4 __attribute__((ext_vector_type(4)));
typedef short s16x8 __attribute__((ext_vector_type(8)));

static __device__ __forceinline__ unsigned f2bf(float f) {
    unsigned u = __float_as_uint(f);
    return (u + 0x7FFFu + ((u >> 16) & 1u)) >> 16;  // RNE
}

// Pre-kernel: A-fragment table in exact MFMA A-operand layout.
// table[g*64 + lane] = 8 bf16 = exp(beta*w[row=lane&15][c=j][tap=g*4+quad]),
// zero for pad taps (>=25) and rows >= 8. 448 entries, 7168 B (L2-hot).
__global__ void build_afrag(const float* __restrict__ wgt,
                            s16x8* __restrict__ table) {
    int i = blockIdx.x * 64 + threadIdx.x;       // 0..447
    if (i >= 7 * 64) return;
    int g = i >> 6, lane = i & 63;
    int quad = lane >> 4, row = lane & 15;
    int tap = g * 4 + quad;
    s16x8 af;
    #pragma unroll
    for (int j = 0; j < CIN; ++j) {
        float v = 0.0f;
        if (tap < 25 && row < COUT)
            v = __expf(BETA * wgt[(row * CIN + j) * (KW * KW) + tap]);
        af[j] = (short)f2bf(v);
    }
    table[i] = af;
}

// Exp-space 5x5 conv as implicit GEMM on matrix cores:
// out = M + log(sum_{c,tap} exp(beta(x-M)) * exp(beta w)) / beta.
// k = tap*8 + c (25 taps padded to 28 = 7 K32 steps; pad rows of A = 0).
//
// R8: WAVE-AUTONOMOUS, ZERO BARRIERS. R3-R7 were phase-locked
// stage->__syncthreads->compute machines; with clean traffic all pipes sat
// <35% (latency-bound). Here each wave stages its own 20x12 halo into a
// private 3840-B LDS slice and computes a 16x8 output tile; LDS write->read
// within one wave needs only the compiler's wave-local lgkmcnt wait, so
// waves never synchronize. The 4 waves of a block tile a 64x8 region so
// full 256-B out rows assemble in the same XCD L2 (keeps WRITE at the
// measured-clean 32.8 MB). Pitch 20 int4 has the same row-to-row bank
// offset (16) as the measured-conflict-free pitch-68 layout.
// launch_bounds min-waves 6 -> 80-VGPR cap (need ~65). NEVER 8: the 64-cap
// spilled afrag in R4/R5 (VGPR_Count 32, 2-4x hbm traffic).
__global__ __launch_bounds__(256, 6) void morph_mfma(
    const float* __restrict__ x, const s16x8* __restrict__ table,
    float* __restrict__ out)
{
    __shared__ int4 exs[4 * WSLOTS];   // 4 waves * 3840 B = 15360 B

    const int tid  = threadIdx.x;
    const int lane = tid & 63;
    const int wv   = tid >> 6;     // wave 0..3 -> cols wv*16 .. wv*16+15
    const int px   = lane & 15;
    const int quad = lane >> 4;

    // XCD-contiguous swizzle: 2048 blocks = 8 XCD * 256; XCD k gets 2 batches.
    const int lid = blockIdx.x;
    const int sw  = (lid & 7) * 256 + (lid >> 3);
    const int b   = sw >> 7;
    const int t   = sw & 127;                 // 32 h-tiles * 4 w-tiles
    const int h0  = (t >> 2) * TWH;
    const int w0  = (t & 3) * 64 + wv * TWW;  // this wave's 16-px column

    int4* myex = &exs[wv * WSLOTS];

    // ---- A fragments: 7 coalesced 16-B loads (L2-hot table) ----
    s16x8 afrag[7];
    int   toff[7];
    #pragma unroll
    for (int g = 0; g < 7; ++g) {
        afrag[g] = table[g * 64 + lane];
        int tap = g * 4 + quad;
        int tc  = tap < 25 ? tap : 24;        // clamp addr; A=0 kills pad taps
        toff[g] = (tc / KW) * WCW + (tc % KW);
    }

    // ---- stage exp(beta*(x-M)) for THIS WAVE's 20x12 halo ----
    for (int s = lane; s < WSLOTS; s += 64) {
        int r = s / WCW, col = s - r * WCW;
        int gh = h0 + r - 2, gw = w0 + col - 2;
        bool ok = ((unsigned)gh < (unsigned)HH) & ((unsigned)gw < (unsigned)WW);
        unsigned pk[4];
        #pragma unroll
        for (int c2 = 0; c2 < 4; ++c2) {
            float v0 = 0.0f, v1 = 0.0f;
            if (ok) {
                v0 = x[((b * CIN + 2 * c2) * HH + gh) * WW + gw];
                v1 = x[((b * CIN + 2 * c2 + 1) * HH + gh) * WW + gw];
            }
            float2 e = make_float2(__expf(BETA * (v0 - MSHIFT)),
                                   __expf(BETA * (v1 - MSHIFT)));
            __hip_bfloat162 h2 = __float22bfloat162_rn(e);  // v_cvt_pk_bf16_f32
            pk[c2] = *reinterpret_cast<unsigned*>(&h2);
        }
        int4 p; p.x = pk[0]; p.y = pk[1]; p.z = pk[2]; p.w = pk[3];
        myex[s] = p;   // lane-contiguous -> conflict-free ds_write_b128
    }
    // NO BARRIER: only this wave reads myex; compiler emits the wave-local
    // s_waitcnt lgkmcnt before the first dependent ds_read.

    // ---- main: 8 rows, 7 MFMA each (K=224); acc chain split 4+3 ----
    const float inv_beta = 1.0f / BETA;
    #pragma unroll
    for (int hl = 0; hl < TWH; ++hl) {
        const int base = hl * WCW + px;
        f32x4 acc0 = {0.0f, 0.0f, 0.0f, 0.0f};
        f32x4 acc1 = {0.0f, 0.0f, 0.0f, 0.0f};
        #pragma unroll
        for (int g = 0; g < 7; ++g) {
            s16x8 bfr = *(const s16x8*)&myex[base + toff[g]];
            if (g & 1)
                acc1 = __builtin_amdgcn_mfma_f32_16x16x32_bf16(
                           afrag[g], bfr, acc1, 0, 0, 0);
            else
                acc0 = __builtin_amdgcn_mfma_f32_16x16x32_bf16(
                           afrag[g], bfr, acc0, 0, 0, 0);
        }
        if (quad < 2) {
            #pragma unroll
            for (int r = 0; r < 4; ++r) {
                int o = quad * 4 + r;
                out[((b * COUT + o) * HH + h0 + hl) * WW + w0 + px]
                    = MSHIFT + __logf(acc0[r] + acc1[r]) * inv_beta;
            }
        }
    }
}

extern "C" void kernel_launch(void* const* d_in, const int* in_sizes, int n_in,
                              void* d_out, int out_size, void* d_ws, size_t ws_size,
                              hipStream_t stream) {
    const float* x   = (const float*)d_in[0];
    const float* wgt = (const float*)d_in[1];
    float* out  = (float*)d_out;
    s16x8* tab  = (s16x8*)d_ws;   // 7168 B

    const int B = in_sizes[0] / (CIN * HH * WW);              // 16
    const int nblk = B * (HH / TWH) * (WW / 64);              // 2048
    build_afrag<<<7, 64, 0, stream>>>(wgt, tab);
    morph_mfma<<<nblk, 256, 0, stream>>>(x, tab, out);
}

// Round 10
// 94.888 us; speedup vs baseline: 1.4732x; 1.0393x over previous
//
#include <hip/hip_runtime.h>
#include <hip/hip_bf16.h>
#include <math.h>

#define KW 5
#define BETA 15.0f
#define MSHIFT 3.0f
#define CIN 8
#define COUT 8
#define HH 256
#define WW 256
#define TWW 16     // wave tile width  (one 16-px MFMA N-group)
#define TWH 8      // wave tile height
#define WCW 20     // TWW + 4 halo
#define WCH 12     // TWH + 4 halo (rows 0..11 serve hl+tr up to 6+5=11)
#define WSLOTS (WCW * WCH)   // 240 slots/wave
#define NG 8       // K-groups: k=(tr 0..5, tc 0..4, c 0..7) = 240 pad 256

typedef float f32x4 __attribute__((ext_vector_type(4)));
typedef short s16x8 __attribute__((ext_vector_type(8)));

static __device__ __forceinline__ unsigned f2bf(float f) {
    unsigned u = __float_as_uint(f);
    return (u + 0x7FFFu + ((u >> 16) & 1u)) >> 16;  // RNE
}

// A-fragment table, exact MFMA A-layout, 2-ROW-PACKED:
//   rows 0-7 : A[o][k=(tr,tc,c)] = exp(beta*w[o][c][tr,tc])   (tr<=4; 0 at tr=5)
//   rows 8-15: A[8+o][k=(tr,tc,c)] = exp(beta*w[o][c][tr-1,tc]) (tr>=1; 0 at tr=0)
// With B[k][px] = EX[hl+tr][px+tc][c], D rows 0-7 = out row hl, rows 8-15 =
// out row hl+1 (index shift Sum_tr W[tr-1] EX[hl+tr] = Sum W[tr'] EX[hl+1+tr']).
// tap30 = g*4+quad in 0..31; 30,31 are zero-pad. 512 entries, 8192 B, L2-hot.
__global__ void build_afrag(const float* __restrict__ wgt,
                            s16x8* __restrict__ table) {
    int i = blockIdx.x * 64 + threadIdx.x;       // 0..511
    int g = i >> 6, lane = i & 63;
    int quad = lane >> 4, row = lane & 15;
    int tap30 = g * 4 + quad;
    int tr = tap30 / KW, tc = tap30 % KW;
    s16x8 af;
    #pragma unroll
    for (int j = 0; j < CIN; ++j) {              // j = c
        float v = 0.0f;
        if (tap30 < 30) {
            if (row < COUT) {
                if (tr <= 4)
                    v = __expf(BETA * wgt[(row * CIN + j) * (KW * KW) + tr * KW + tc]);
            } else {
                if (tr >= 1)
                    v = __expf(BETA * wgt[((row - 8) * CIN + j) * (KW * KW) + (tr - 1) * KW + tc]);
            }
        }
        af[j] = (short)f2bf(v);
    }
    table[i] = af;
}

// Exp-space 5x5 conv as implicit GEMM, wave-autonomous (R8), 2-row-packed (R9):
// out = M + log(sum exp(beta(x-M)) * exp(beta w)) / beta.
// Per hl-pair: 8 ds_read_b128 + 8 MFMA -> 16 px * 2 rows * 8 o  (R8 needed
// 14+14 for the same outputs). Epilogue full-exec: quad -> (dh=quad>>1,
// o=(quad&1)*4+reg).
// launch_bounds min-waves 5 -> ~102-VGPR cap (need ~85). NEVER 8: 64-cap
// spilled afrag in R4/R5 (VGPR_Count 32, 2-4x hbm traffic).
__global__ __launch_bounds__(256, 5) void morph_mfma(
    const float* __restrict__ x, const s16x8* __restrict__ table,
    float* __restrict__ out)
{
    __shared__ int4 exs[4 * WSLOTS];   // 4 waves * 3840 B = 15360 B

    const int tid  = threadIdx.x;
    const int lane = tid & 63;
    const int wv   = tid >> 6;
    const int px   = lane & 15;
    const int quad = lane >> 4;

    // XCD-contiguous swizzle: 2048 blocks = 8 XCD * 256; XCD k gets 2 batches.
    const int lid = blockIdx.x;
    const int sw  = (lid & 7) * 256 + (lid >> 3);
    const int b   = sw >> 7;
    const int t   = sw & 127;                 // 32 h-tiles * 4 w-tiles
    const int h0  = (t >> 2) * TWH;
    const int w0  = (t & 3) * 64 + wv * TWW;  // this wave's 16-px column

    int4* myex = &exs[wv * WSLOTS];

    // ---- A fragments: 8 coalesced 16-B loads (L2-hot table) ----
    s16x8 afrag[NG];
    int   toff[NG];
    #pragma unroll
    for (int g = 0; g < NG; ++g) {
        afrag[g] = table[g * 64 + lane];
        int tap30 = g * 4 + quad;
        int tcl   = tap30 < 30 ? tap30 : 29;  // clamp addr; A=0 kills pads
        toff[g] = (tcl / KW) * WCW + (tcl % KW);
    }

    // ---- stage exp(beta*(x-M)) for THIS WAVE's 20x12 halo ----
    for (int s = lane; s < WSLOTS; s += 64) {
        int r = s / WCW, col = s - r * WCW;
        int gh = h0 + r - 2, gw = w0 + col - 2;
        bool ok = ((unsigned)gh < (unsigned)HH) & ((unsigned)gw < (unsigned)WW);
        unsigned pk[4];
        #pragma unroll
        for (int c2 = 0; c2 < 4; ++c2) {
            float v0 = 0.0f, v1 = 0.0f;
            if (ok) {
                v0 = x[((b * CIN + 2 * c2) * HH + gh) * WW + gw];
                v1 = x[((b * CIN + 2 * c2 + 1) * HH + gh) * WW + gw];
            }
            // exp(beta*(v-M)) = 2^(v*beta*log2e - beta*M*log2e): 1 fma + v_exp
            float2 e = make_float2(
                __builtin_amdgcn_exp2f(fmaf(v0, 21.6404256f, -64.9212768f)),
                __builtin_amdgcn_exp2f(fmaf(v1, 21.6404256f, -64.9212768f)));
            __hip_bfloat162 h2 = __float22bfloat162_rn(e);
            pk[c2] = *reinterpret_cast<unsigned*>(&h2);
        }
        int4 p; p.x = pk[0]; p.y = pk[1]; p.z = pk[2]; p.w = pk[3];
        myex[s] = p;   // lane-contiguous -> conflict-free ds_write_b128
    }
    // No barrier: wave-private slice; compiler's lgkmcnt covers write->read.

    // ---- main: 4 hl-pairs, 8 MFMA each (K=256, 240 used) ----
    const int dh = quad >> 1;            // which of the 2 packed out rows
    const int ob = (quad & 1) * 4;       // o base for this quad
    const float LN2B = 0.04620981f;      // ln2 / beta
    #pragma unroll
    for (int hp = 0; hp < 4; ++hp) {
        const int base = (2 * hp) * WCW + px;
        f32x4 acc0 = {0.0f, 0.0f, 0.0f, 0.0f};
        f32x4 acc1 = {0.0f, 0.0f, 0.0f, 0.0f};
        #pragma unroll
        for (int g = 0; g < NG; ++g) {
            s16x8 bfr = *(const s16x8*)&myex[base + toff[g]];
            if (g & 1)
                acc1 = __builtin_amdgcn_mfma_f32_16x16x32_bf16(
                           afrag[g], bfr, acc1, 0, 0, 0);
            else
                acc0 = __builtin_amdgcn_mfma_f32_16x16x32_bf16(
                           afrag[g], bfr, acc0, 0, 0, 0);
        }
        const int h = h0 + 2 * hp + dh;
        #pragma unroll
        for (int r = 0; r < 4; ++r) {
            float s = acc0[r] + acc1[r];
            // out = M + log2(s) * ln2/beta   (v_log_f32 is log2)
            out[((b * COUT + ob + r) * HH + h) * WW + w0 + px]
                = fmaf(__builtin_amdgcn_logf(s), LN2B, MSHIFT);
        }
    }
}

extern "C" void kernel_launch(void* const* d_in, const int* in_sizes, int n_in,
                              void* d_out, int out_size, void* d_ws, size_t ws_size,
                              hipStream_t stream) {
    const float* x   = (const float*)d_in[0];
    const float* wgt = (const float*)d_in[1];
    float* out  = (float*)d_out;
    s16x8* tab  = (s16x8*)d_ws;   // 8192 B

    const int B = in_sizes[0] / (CIN * HH * WW);              // 16
    const int nblk = B * (HH / TWH) * (WW / 64);              // 2048
    build_afrag<<<NG, 64, 0, stream>>>(wgt, tab);
    morph_mfma<<<nblk, 256, 0, stream>>>(x, tab, out);
}